// Round 3
// baseline (1387.487 us; speedup 1.0000x reference)
//
#include <hip/hip_runtime.h>

typedef _Float16 f16x8 __attribute__((ext_vector_type(8)));
typedef _Float16 f16x2 __attribute__((ext_vector_type(2)));
typedef float f32x4 __attribute__((ext_vector_type(4)));

constexpr int D = 256;
constexpr int NUTT = 64;
constexpr int L = 512;
constexpr int G = 768;           // 3*D

// LDS-only barrier: orders ds_* ops across the workgroup WITHOUT draining
// vmcnt — global prefetch loads / wo stores stay in flight across steps.
__device__ __forceinline__ void lds_barrier() {
  asm volatile("s_waitcnt lgkmcnt(0)\n\ts_barrier" ::: "memory");
}

__device__ __forceinline__ float fdot2(f16x2 a, f16x2 b, float c) {
#if defined(__has_builtin)
#if __has_builtin(__builtin_amdgcn_fdot2)
  return __builtin_amdgcn_fdot2(a, b, c, false);
#else
  return c + (float)a.x * (float)b.x + (float)a.y * (float)b.y;
#endif
#else
  return c + (float)a.x * (float)b.x + (float)a.y * (float)b.y;
#endif
}

__device__ __forceinline__ float fast_rcp(float x) {
  return __builtin_amdgcn_rcpf(x);
}
__device__ __forceinline__ float sigm(float x) {
  return fast_rcp(1.0f + __expf(-x));
}
__device__ __forceinline__ float tanh_f(float x) {
  float ax = fabsf(x);
  float e = __expf(-2.0f * ax);
  float r = (1.0f - e) * fast_rcp(1.0f + e);
  return copysignf(r, x);
}

// ---------------------------------------------------------------------------
// Kernel B: gx[m][g] = embed[tokens[m]][:] . Wih[g][:] + bih[g]
// m = b*L + t  (M = 32768), g in [0,768).  Tiled fp32 GEMM, BM=64 BN=128 BK=32
// ---------------------------------------------------------------------------
__global__ __launch_bounds__(256) void gx_gemm(
    const int* __restrict__ tokens, const float* __restrict__ embed,
    const float* __restrict__ Wih, const float* __restrict__ bih,
    float* __restrict__ gx) {
  __shared__ float As[64][33];
  __shared__ float Bs[32][129];
  __shared__ int toks[64];

  const int tid = threadIdx.x;
  const int m0 = blockIdx.x * 64;
  const int n0 = blockIdx.y * 128;
  if (tid < 64) toks[tid] = tokens[m0 + tid];
  __syncthreads();

  const int ty = tid >> 4;   // 0..15 : row group (4 rows each)
  const int tx = tid & 15;   // 0..15 : col base (cols tx + 16*cc)
  float acc[4][8] = {};

  for (int k0 = 0; k0 < 256; k0 += 32) {
    // stage A (embedding gather rows)
    {
      const int i = tid >> 2;            // 0..63
      const int kq = (tid & 3) * 4;      // 0,4,8,12
      const float* src = embed + (size_t)toks[i] * D + k0;
      float4 v0 = *(const float4*)(src + kq);
      float4 v1 = *(const float4*)(src + kq + 16);
      As[i][kq + 0] = v0.x; As[i][kq + 1] = v0.y;
      As[i][kq + 2] = v0.z; As[i][kq + 3] = v0.w;
      As[i][kq + 16] = v1.x; As[i][kq + 17] = v1.y;
      As[i][kq + 18] = v1.z; As[i][kq + 19] = v1.w;
    }
    // stage B (weights, transposed into [k][g])
    {
      const int goff = tid >> 3;         // 0..31
      const int kq = (tid & 7) * 4;      // 0..28
      for (int gp = 0; gp < 128; gp += 32) {
        const float* src = Wih + (size_t)(n0 + goff + gp) * D + k0 + kq;
        float4 v = *(const float4*)src;
        Bs[kq + 0][goff + gp] = v.x;
        Bs[kq + 1][goff + gp] = v.y;
        Bs[kq + 2][goff + gp] = v.z;
        Bs[kq + 3][goff + gp] = v.w;
      }
    }
    __syncthreads();
    const int r0 = ty * 4;
#pragma unroll 4
    for (int k = 0; k < 32; ++k) {
      float a0 = As[r0 + 0][k], a1 = As[r0 + 1][k];
      float a2 = As[r0 + 2][k], a3 = As[r0 + 3][k];
#pragma unroll
      for (int cc = 0; cc < 8; ++cc) {
        float bv = Bs[k][tx + 16 * cc];
        acc[0][cc] = fmaf(a0, bv, acc[0][cc]);
        acc[1][cc] = fmaf(a1, bv, acc[1][cc]);
        acc[2][cc] = fmaf(a2, bv, acc[2][cc]);
        acc[3][cc] = fmaf(a3, bv, acc[3][cc]);
      }
    }
    __syncthreads();
  }
#pragma unroll
  for (int rr = 0; rr < 4; ++rr) {
    float* dst = gx + (size_t)(m0 + ty * 4 + rr) * G + n0;
#pragma unroll
    for (int cc = 0; cc < 8; ++cc) {
      int c = tx + 16 * cc;
      dst[c] = acc[rr][cc] + bih[n0 + c];
    }
  }
}

// ---------------------------------------------------------------------------
// Kernel C: persistent word-GRU scan — hybrid MFMA ∥ VALU edition.
// Rationale (R2 counters): pure-MFMA floor = 96 mfma/SIMD/step x 19.4 cyc
// = 1863 cyc (16x M-broadcast waste -> useful 53 FLOP/cyc/SIMD). Pure-VALU
// dot2 floor (R0 data, 4.8 cyc/dot2) = the SAME 53 FLOP/cyc/SIMD. The pipes
// are separate (m114) -> run both: each wave owns 96 cols,
//   48 cols via 3 MFMA tiles  (Bf = 96 regs, AGPR-eligible),
//   32 cols via per-lane K-half dot2   (col = 96w+48+(lane&31), kh=lane>>5),
//   16 cols via per-lane K-quarter dot2 (col = 96w+80+(lane&15), kq=lane>>4),
// with shfl_xor partial-sum reduces for the split-K cols.
// Per SIMD/step: 48 mfma (~930 cyc matrix pipe) || 192 dot2 (~920 cyc VALU).
// 64 WGs x 512 threads (8 waves, 2/SIMD). Barriers LDS-only.
// ---------------------------------------------------------------------------
__global__ __launch_bounds__(512, 2) void gru_scan_word(
    const float* __restrict__ gx,    // [NUTT][L][G] (includes b_ih)
    const float* __restrict__ Whh,   // [G][D]
    const float* __restrict__ bhh,   // [G]
    float* __restrict__ wo) {        // [NUTT][L][D]
  __shared__ __align__(16) _Float16 hbuf[2][D];   // f16 h, double-buffered
  __shared__ __align__(16) float pre4[D][4];      // [d] = {aR, aZ, aN, -}

  const int t = threadIdx.x;          // updater: t < 256, d = t
  const int b = blockIdx.x;
  const int w = t >> 6;               // wave 0..7
  const int lane = t & 63;
  const int l15 = lane & 15;          // MFMA B col / D col within tile
  const int lk = lane >> 4;           // MFMA k-subgroup 0..3

  // ---- MFMA B fragments: 3 tiles, Bf[i][f][j] = Whh[n][32f+8lk+j], f16 ----
  f16x8 Bf[3][8];
#pragma unroll
  for (int i = 0; i < 3; ++i) {
    const float* row = Whh + (size_t)(96 * w + 16 * i + l15) * D + 8 * lk;
#pragma unroll
    for (int f = 0; f < 8; ++f) {
      float4 v0 = *(const float4*)(row + 32 * f);
      float4 v1 = *(const float4*)(row + 32 * f + 4);
      Bf[i][f] = f16x8{(_Float16)v0.x, (_Float16)v0.y,
                       (_Float16)v0.z, (_Float16)v0.w,
                       (_Float16)v1.x, (_Float16)v1.y,
                       (_Float16)v1.z, (_Float16)v1.w};
    }
  }

  // ---- VALU weights: A-cols (K-half) and B-cols (K-quarter), f16 pairs ----
  const int khA = lane >> 5;                 // 0,1
  const int kqB = lane >> 4;                 // 0..3
  f16x2 wA[64];                              // 128 K-elems of col 96w+48+(lane&31)
  {
    const float* row = Whh + (size_t)(96 * w + 48 + (lane & 31)) * D + khA * 128;
#pragma unroll
    for (int c = 0; c < 32; ++c) {
      float4 v = *(const float4*)(row + 4 * c);
      wA[2 * c]     = f16x2{(_Float16)v.x, (_Float16)v.y};
      wA[2 * c + 1] = f16x2{(_Float16)v.z, (_Float16)v.w};
    }
  }
  f16x2 wB[32];                              // 64 K-elems of col 96w+80+(lane&15)
  {
    const float* row = Whh + (size_t)(96 * w + 80 + l15) * D + kqB * 64;
#pragma unroll
    for (int c = 0; c < 16; ++c) {
      float4 v = *(const float4*)(row + 4 * c);
      wB[2 * c]     = f16x2{(_Float16)v.x, (_Float16)v.y};
      wB[2 * c + 1] = f16x2{(_Float16)v.z, (_Float16)v.w};
    }
  }

  float bR = 0.0f, bZ = 0.0f, bN = 0.0f;
  float gr = 0.0f, gz = 0.0f, gn = 0.0f;
  const float* gxb = gx + (size_t)b * L * G;
  if (t < 256) {
    bR = bhh[t]; bZ = bhh[D + t]; bN = bhh[2 * D + t];
    gr = gxb[t]; gz = gxb[D + t]; gn = gxb[2 * D + t];
    hbuf[0][t] = (_Float16)0.0f;
  }
  float hprev = 0.0f;
  float* wob = wo + (size_t)b * L * D;
  __syncthreads();

  for (int ts = 0; ts < L; ++ts) {
    const int cur = ts & 1;
    const _Float16* hb = hbuf[cur];

    // --- MFMA part first (fills matrix pipe; VALU loop runs concurrent) ---
    f16x8 A[8];
#pragma unroll
    for (int f = 0; f < 8; ++f)
      A[f] = *(const f16x8*)(hb + 32 * f + 8 * lk);

    f32x4 acc0 = {0.f, 0.f, 0.f, 0.f};
    f32x4 acc1 = {0.f, 0.f, 0.f, 0.f};
    f32x4 acc2 = {0.f, 0.f, 0.f, 0.f};
#pragma unroll
    for (int f = 0; f < 8; ++f) {
      acc0 = __builtin_amdgcn_mfma_f32_16x16x32_f16(A[f], Bf[0][f], acc0, 0, 0, 0);
      acc1 = __builtin_amdgcn_mfma_f32_16x16x32_f16(A[f], Bf[1][f], acc1, 0, 0, 0);
      acc2 = __builtin_amdgcn_mfma_f32_16x16x32_f16(A[f], Bf[2][f], acc2, 0, 0, 0);
    }

    // --- VALU part: dot2 over K-half (A-cols) and K-quarter (B-cols) ---
    const f16x8* hA8 = (const f16x8*)(hb + khA * 128);   // 16 chunks of 8
    const f16x8* hB8 = (const f16x8*)(hb + kqB * 64);    // 8 chunks of 8
    float pA0 = 0.0f, pA1 = 0.0f, pB0 = 0.0f, pB1 = 0.0f;
#pragma unroll
    for (int c = 0; c < 16; ++c) {
      union { f16x8 v; f16x2 h[4]; } U;
      U.v = hA8[c];
      pA0 = fdot2(wA[4 * c + 0], U.h[0], pA0);
      pA1 = fdot2(wA[4 * c + 1], U.h[1], pA1);
      pA0 = fdot2(wA[4 * c + 2], U.h[2], pA0);
      pA1 = fdot2(wA[4 * c + 3], U.h[3], pA1);
    }
#pragma unroll
    for (int c = 0; c < 8; ++c) {
      union { f16x8 v; f16x2 h[4]; } U;
      U.v = hB8[c];
      pB0 = fdot2(wB[4 * c + 0], U.h[0], pB0);
      pB1 = fdot2(wB[4 * c + 1], U.h[1], pB1);
      pB0 = fdot2(wB[4 * c + 2], U.h[2], pB0);
      pB1 = fdot2(wB[4 * c + 3], U.h[3], pB1);
    }

    // --- reduce split-K partials and publish all 96 cols of this wave ---
    float pA = pA0 + pA1;
    pA += __shfl_xor(pA, 32);            // combine the two K-halves
    float pB = pB0 + pB1;
    pB += __shfl_xor(pB, 16);            // combine the four K-quarters
    pB += __shfl_xor(pB, 32);

    if (lane < 32) {
      const int n = 96 * w + 48 + lane;
      pre4[n & 255][n >> 8] = pA;
    }
    if (lane < 16) {
      const int n = 96 * w + 80 + lane;
      pre4[n & 255][n >> 8] = pB;
    }
    if (lk == 0) {                       // mfma tiles: lanes 0-15 publish
      const int n0t = 96 * w + l15;
      pre4[n0t & 255][n0t >> 8] = acc0[0];
      const int n1t = 96 * w + 16 + l15;
      pre4[n1t & 255][n1t >> 8] = acc1[0];
      const int n2t = 96 * w + 32 + l15;
      pre4[n2t & 255][n2t >> 8] = acc2[0];
    }
    lds_barrier();

    if (t < 256) {
      float4 pa = *(const float4*)pre4[t];   // {aR, aZ, aN, -}
      float r = sigm(gr + pa.x + bR);
      float z = sigm(gz + pa.y + bZ);
      float nn = tanh_f(gn + r * (pa.z + bN));
      float hn = fmaf(z, hprev - nn, nn);    // (1-z)*n + z*h
      hprev = hn;
      hbuf[cur ^ 1][t] = (_Float16)hn;
      wob[(size_t)ts * D + t] = hn;
      const int tn = (ts + 1 < L) ? ts + 1 : ts;
      const float* gxn = gxb + (size_t)tn * G;
      gr = gxn[t]; gz = gxn[D + t]; gn = gxn[2 * D + t];
    }
    lds_barrier();
  }
}

// ---------------------------------------------------------------------------
// Kernel D: attention pool over word_out -> utt[64][256]
// ---------------------------------------------------------------------------
__global__ __launch_bounds__(256) void attn_pool_word(
    const float* __restrict__ wo, const float* __restrict__ uaw,
    float* __restrict__ utt) {
  __shared__ float wsh[D];
  __shared__ float lg[L];
  __shared__ float red[8];
  const int tid = threadIdx.x, b = blockIdx.x;
  wsh[tid] = uaw[tid];
  __syncthreads();

  const int wid = tid >> 6, lane = tid & 63;
  const float* base = wo + (size_t)b * L * D;
  for (int t = wid; t < L; t += 4) {
    const float* row = base + (size_t)t * D;
    float p = 0.0f;
#pragma unroll
    for (int j = 0; j < 4; ++j) p = fmaf(row[lane + 64 * j], wsh[lane + 64 * j], p);
#pragma unroll
    for (int off = 32; off; off >>= 1) p += __shfl_down(p, off);
    if (lane == 0) lg[t] = p;                  // ua_b cancels in softmax
  }
  __syncthreads();

  float m = fmaxf(lg[tid], lg[tid + 256]);
#pragma unroll
  for (int off = 32; off; off >>= 1) m = fmaxf(m, __shfl_down(m, off));
  if (lane == 0) red[wid] = m;
  __syncthreads();
  m = fmaxf(fmaxf(red[0], red[1]), fmaxf(red[2], red[3]));

  float e0 = __expf(lg[tid] - m), e1 = __expf(lg[tid + 256] - m);
  float s = e0 + e1;
#pragma unroll
  for (int off = 32; off; off >>= 1) s += __shfl_down(s, off);
  if (lane == 0) red[4 + wid] = s;
  __syncthreads();
  s = red[4] + red[5] + red[6] + red[7];
  float inv = 1.0f / s;
  lg[tid] = e0 * inv;
  lg[tid + 256] = e1 * inv;
  __syncthreads();

  float acc = 0.0f;
#pragma unroll 4
  for (int t = 0; t < L; ++t) acc = fmaf(lg[t], base[(size_t)t * D + tid], acc);
  utt[(size_t)b * D + tid] = acc;
}

// ---------------------------------------------------------------------------
// Kernel E: sentence GRU (T=1, h0=0) -> dialog_vec = (1-z)*n
// ---------------------------------------------------------------------------
__global__ __launch_bounds__(256) void sent_kernel(
    const float* __restrict__ utt, const float* __restrict__ Wih,
    const float* __restrict__ bih, const float* __restrict__ bhh,
    float* __restrict__ out) {
  __shared__ float u[D];
  const int d = threadIdx.x, b = blockIdx.x;
  u[d] = utt[(size_t)b * D + d];
  __syncthreads();

  const float* wr = Wih + (size_t)d * D;
  const float* wz = Wih + (size_t)(D + d) * D;
  const float* wn = Wih + (size_t)(2 * D + d) * D;
  float ar = 0.0f, az = 0.0f, an = 0.0f;
  for (int k = 0; k < D; k += 4) {
    float4 vr = *(const float4*)(wr + k);
    float4 vz = *(const float4*)(wz + k);
    float4 vn = *(const float4*)(wn + k);
    float u0 = u[k], u1 = u[k + 1], u2 = u[k + 2], u3 = u[k + 3];
    ar += vr.x * u0 + vr.y * u1 + vr.z * u2 + vr.w * u3;
    az += vz.x * u0 + vz.y * u1 + vz.z * u2 + vz.w * u3;
    an += vn.x * u0 + vn.y * u1 + vn.z * u2 + vn.w * u3;
  }
  float xr = ar + bih[d];
  float xz = az + bih[D + d];
  float xn = an + bih[2 * D + d];
  float r = sigm(xr + bhh[d]);
  float z = sigm(xz + bhh[D + d]);
  float n = tanh_f(xn + r * bhh[2 * D + d]);
  out[(size_t)b * D + d] = (1.0f - z) * n;
}

// ---------------------------------------------------------------------------
extern "C" void kernel_launch(void* const* d_in, const int* in_sizes, int n_in,
                              void* d_out, int out_size, void* d_ws, size_t ws_size,
                              hipStream_t stream) {
  const int* tokens    = (const int*)d_in[0];
  const float* embed   = (const float*)d_in[1];
  const float* wg_Wih  = (const float*)d_in[2];
  const float* wg_Whh  = (const float*)d_in[3];
  const float* wg_bih  = (const float*)d_in[4];
  const float* wg_bhh  = (const float*)d_in[5];
  const float* ua_w    = (const float*)d_in[6];
  // d_in[7] ua_b: softmax shift-invariant -> unused
  const float* sg_Wih  = (const float*)d_in[8];
  // d_in[9] sg_Whh: h0 == 0 -> unused
  const float* sg_bih  = (const float*)d_in[10];
  const float* sg_bhh  = (const float*)d_in[11];
  // d_in[12..13] da_w/da_b: softmax over T=1 -> unused
  float* out = (float*)d_out;

  char* ws = (char*)d_ws;
  float* gx  = (float*)ws;                                     // 96 MB
  float* wo  = (float*)(ws + (size_t)NUTT * L * G * 4);        // 32 MB
  float* utt = (float*)(ws + (size_t)NUTT * L * G * 4
                           + (size_t)NUTT * L * D * 4);        // 64 KB

  dim3 gB(512, 6);
  gx_gemm<<<gB, 256, 0, stream>>>(tokens, embed, wg_Wih, wg_bih, gx);
  gru_scan_word<<<NUTT, 512, 0, stream>>>(gx, wg_Whh, wg_bhh, wo);
  attn_pool_word<<<NUTT, 256, 0, stream>>>(wo, ua_w, utt);
  sent_kernel<<<NUTT, 256, 0, stream>>>(utt, sg_Wih, sg_bih, sg_bhh, out);
}

// Round 5
// 970.801 us; speedup vs baseline: 1.4292x; 1.4292x over previous
//
#include <hip/hip_runtime.h>

typedef _Float16 f16x8 __attribute__((ext_vector_type(8)));
typedef float f32x4 __attribute__((ext_vector_type(4)));

constexpr int D = 256;
constexpr int NUTT = 64;
constexpr int L = 512;
constexpr int G = 768;           // 3*D

// LDS-only barrier: orders ds_* ops across the workgroup WITHOUT draining
// vmcnt — global prefetch loads / wo stores stay in flight across steps.
__device__ __forceinline__ void lds_barrier() {
  asm volatile("s_waitcnt lgkmcnt(0)\n\ts_barrier" ::: "memory");
}

__device__ __forceinline__ float fast_rcp(float x) {
  return __builtin_amdgcn_rcpf(x);
}
__device__ __forceinline__ float sigm(float x) {
  return fast_rcp(1.0f + __expf(-x));
}
__device__ __forceinline__ float tanh_f(float x) {
  float ax = fabsf(x);
  float e = __expf(-2.0f * ax);
  float r = (1.0f - e) * fast_rcp(1.0f + e);
  return copysignf(r, x);
}

// ---------------------------------------------------------------------------
// Kernel A: split Wih (f32) into f16 hi/lo pair for split-f16 MFMA GEMM.
// hi = f16(v), lo = f16(v - hi).  3-term product expansion (drops lo*lo)
// has ~2^-22 relative error — f32-equivalent for this data.
// ---------------------------------------------------------------------------
__global__ __launch_bounds__(256) void split_wih(
    const float* __restrict__ Wih, _Float16* __restrict__ hi,
    _Float16* __restrict__ lo) {
  const int i = blockIdx.x * 256 + threadIdx.x;    // grid = 768 blocks
  float v = Wih[i];
  _Float16 h = (_Float16)v;
  hi[i] = h;
  lo[i] = (_Float16)(v - (float)h);
}

// ---------------------------------------------------------------------------
// Kernel B: gx[m][g] = embed[tokens[m]][:] . Wih[g][:] + bih[g]
// MFMA split-f16, LDS-free edition (R4's As[64][68] staging aliased at
// 256-col indexing AND overran into toks[] — root cause of the 3e-2 fail;
// direct global fragment reads eliminate the staging entirely).
// M=32768, N=768, K=256. BM=64 (4 waves x 16 rows), BN=128 (8 16-col tiles).
// A fragment: lane reads 32 contiguous bytes of its row's K-slice straight
// from embed (L3-resident, 16B-aligned), converts to f16 hi/lo in regs.
// B streamed from pre-split whi/wlo (1.5 MB — L2-resident).
// 3 mfma per (tile,f): Ahi*Bhi + Alo*Bhi + Ahi*Blo (f32 accum).
// Fragment maps (all verified): A row = lane&15, k = 32f+8*(lane>>4)+j
// (same k-packing both operands — pairing cancels, proven by gru kernel);
// D col = lane&15, row = 4*(lane>>4)+reg  [m89].
// ---------------------------------------------------------------------------
__global__ __launch_bounds__(256) void gx_gemm_mfma(
    const int* __restrict__ tokens, const float* __restrict__ embed,
    const _Float16* __restrict__ whi, const _Float16* __restrict__ wlo,
    const float* __restrict__ bih, float* __restrict__ gx) {
  const int tid = threadIdx.x;
  const int m0 = blockIdx.x * 64;
  const int n0 = blockIdx.y * 128;

  const int w = tid >> 6;                // wave 0..3
  const int lane = tid & 63;
  const int l15 = lane & 15;
  const int lk = lane >> 4;

  const int tok = tokens[m0 + 16 * w + l15];
  const float* arow = embed + (size_t)tok * D;

  f32x4 acc[8] = {};
  const _Float16* bh0 = whi + (size_t)(n0 + l15) * D + 8 * lk;
  const _Float16* bl0 = wlo + (size_t)(n0 + l15) * D + 8 * lk;

#pragma unroll
  for (int f = 0; f < 8; ++f) {
    // A fragment: 32B of this lane's row, f32 -> (hi, lo) f16x8
    const float* ap = arow + 32 * f + 8 * lk;
    float4 v0 = *(const float4*)(ap);
    float4 v1 = *(const float4*)(ap + 4);
    float av[8] = {v0.x, v0.y, v0.z, v0.w, v1.x, v1.y, v1.z, v1.w};
    f16x8 ahi, alo;
#pragma unroll
    for (int j = 0; j < 8; ++j) {
      _Float16 h = (_Float16)av[j];
      ahi[j] = h;
      alo[j] = (_Float16)(av[j] - (float)h);
    }
#pragma unroll
    for (int i = 0; i < 8; ++i) {
      f16x8 bhi = *(const f16x8*)(bh0 + (size_t)(16 * i) * D + 32 * f);
      f16x8 blo = *(const f16x8*)(bl0 + (size_t)(16 * i) * D + 32 * f);
      acc[i] = __builtin_amdgcn_mfma_f32_16x16x32_f16(ahi, bhi, acc[i], 0, 0, 0);
      acc[i] = __builtin_amdgcn_mfma_f32_16x16x32_f16(alo, bhi, acc[i], 0, 0, 0);
      acc[i] = __builtin_amdgcn_mfma_f32_16x16x32_f16(ahi, blo, acc[i], 0, 0, 0);
    }
  }

  // epilogue: D row = 4*lk + reg (within wave's 16-row strip), col = l15
#pragma unroll
  for (int i = 0; i < 8; ++i) {
    const int n = n0 + 16 * i + l15;
    const float bb = bih[n];
#pragma unroll
    for (int reg = 0; reg < 4; ++reg) {
      const int m = m0 + 16 * w + 4 * lk + reg;
      gx[(size_t)m * G + n] = acc[i][reg] + bb;
    }
  }
}

// ---------------------------------------------------------------------------
// Kernel C: persistent word-GRU scan — MFMA edition (R2-verified, 580 µs),
// with pre-activation buffer switched to SoA (pre[3][D]) to kill the 8-way
// bank conflict on the updater's float4 read (R2: 1.57M SQ_LDS_BANK_CONFLICT).
// 64 WGs x 512 threads (8 waves, 2/SIMD). Wave w owns cols [96w, 96w+96):
// 6 16-col tiles; Bf = 6x8 f16x8 = 192 regs, loop-invariant.
// ---------------------------------------------------------------------------
__global__ __launch_bounds__(512, 2) void gru_scan_word(
    const float* __restrict__ gx,    // [NUTT][L][G] (includes b_ih)
    const float* __restrict__ Whh,   // [G][D]
    const float* __restrict__ bhh,   // [G]
    float* __restrict__ wo) {        // [NUTT][L][D]
  __shared__ __align__(16) _Float16 hbuf[2][D];   // f16 h, double-buffered
  __shared__ float pre[3][D];                     // [comp][d] = aR/aZ/aN

  const int t = threadIdx.x;          // updater: t < 256, d = t
  const int b = blockIdx.x;
  const int w = t >> 6;               // wave 0..7
  const int lane = t & 63;
  const int l15 = lane & 15;          // B col / D col within tile
  const int lk = lane >> 4;           // k-subgroup 0..3

  // ---- preload B fragments: Bf[i][f][j] = Whh[n][32f + 8lk + j], f16 ----
  f16x8 Bf[6][8];
#pragma unroll
  for (int i = 0; i < 6; ++i) {
    const float* row = Whh + (size_t)(96 * w + 16 * i + l15) * D + 8 * lk;
#pragma unroll
    for (int f = 0; f < 8; ++f) {
      float4 v0 = *(const float4*)(row + 32 * f);
      float4 v1 = *(const float4*)(row + 32 * f + 4);
      Bf[i][f] = f16x8{(_Float16)v0.x, (_Float16)v0.y,
                       (_Float16)v0.z, (_Float16)v0.w,
                       (_Float16)v1.x, (_Float16)v1.y,
                       (_Float16)v1.z, (_Float16)v1.w};
    }
  }

  float bR = 0.0f, bZ = 0.0f, bN = 0.0f;
  float gr = 0.0f, gz = 0.0f, gn = 0.0f;
  const float* gxb = gx + (size_t)b * L * G;
  if (t < 256) {
    bR = bhh[t]; bZ = bhh[D + t]; bN = bhh[2 * D + t];
    gr = gxb[t]; gz = gxb[D + t]; gn = gxb[2 * D + t];
    hbuf[0][t] = (_Float16)0.0f;
  }
  float hprev = 0.0f;
  float* wob = wo + (size_t)b * L * D;
  __syncthreads();

  for (int ts = 0; ts < L; ++ts) {
    const int cur = ts & 1;

    // A fragments: broadcast h (identical within each 16-lane k-group)
    const _Float16* hb = hbuf[cur];
    f16x8 A[8];
#pragma unroll
    for (int f = 0; f < 8; ++f)
      A[f] = *(const f16x8*)(hb + 32 * f + 8 * lk);

#pragma unroll
    for (int i = 0; i < 6; ++i) {
      f32x4 acc = {0.0f, 0.0f, 0.0f, 0.0f};
#pragma unroll
      for (int f = 0; f < 8; ++f)
        acc = __builtin_amdgcn_mfma_f32_16x16x32_f16(A[f], Bf[i][f], acc,
                                                     0, 0, 0);
      if (lk == 0) {                    // all D rows equal; lanes 0-15 write
        const int n = 96 * w + 16 * i + l15;
        pre[n >> 8][n & 255] = acc[0];
      }
    }
    lds_barrier();

    if (t < 256) {
      float aR = pre[0][t], aZ = pre[1][t], aN = pre[2][t];
      float r = sigm(gr + aR + bR);
      float z = sigm(gz + aZ + bZ);
      float nn = tanh_f(gn + r * (aN + bN));
      float hn = fmaf(z, hprev - nn, nn);    // (1-z)*n + z*h
      hprev = hn;
      hbuf[cur ^ 1][t] = (_Float16)hn;
      wob[(size_t)ts * D + t] = hn;
      const int tn = (ts + 1 < L) ? ts + 1 : ts;
      const float* gxn = gxb + (size_t)tn * G;
      gr = gxn[t]; gz = gxn[D + t]; gn = gxn[2 * D + t];
    }
    lds_barrier();
  }
}

// ---------------------------------------------------------------------------
// Kernel D: attention pool over word_out -> utt[64][256]
// ---------------------------------------------------------------------------
__global__ __launch_bounds__(256) void attn_pool_word(
    const float* __restrict__ wo, const float* __restrict__ uaw,
    float* __restrict__ utt) {
  __shared__ float wsh[D];
  __shared__ float lg[L];
  __shared__ float red[8];
  const int tid = threadIdx.x, b = blockIdx.x;
  wsh[tid] = uaw[tid];
  __syncthreads();

  const int wid = tid >> 6, lane = tid & 63;
  const float* base = wo + (size_t)b * L * D;
  for (int t = wid; t < L; t += 4) {
    const float* row = base + (size_t)t * D;
    float p = 0.0f;
#pragma unroll
    for (int j = 0; j < 4; ++j) p = fmaf(row[lane + 64 * j], wsh[lane + 64 * j], p);
#pragma unroll
    for (int off = 32; off; off >>= 1) p += __shfl_down(p, off);
    if (lane == 0) lg[t] = p;                  // ua_b cancels in softmax
  }
  __syncthreads();

  float m = fmaxf(lg[tid], lg[tid + 256]);
#pragma unroll
  for (int off = 32; off; off >>= 1) m = fmaxf(m, __shfl_down(m, off));
  if (lane == 0) red[wid] = m;
  __syncthreads();
  m = fmaxf(fmaxf(red[0], red[1]), fmaxf(red[2], red[3]));

  float e0 = __expf(lg[tid] - m), e1 = __expf(lg[tid + 256] - m);
  float s = e0 + e1;
#pragma unroll
  for (int off = 32; off; off >>= 1) s += __shfl_down(s, off);
  if (lane == 0) red[4 + wid] = s;
  __syncthreads();
  s = red[4] + red[5] + red[6] + red[7];
  float inv = 1.0f / s;
  lg[tid] = e0 * inv;
  lg[tid + 256] = e1 * inv;
  __syncthreads();

  float acc = 0.0f;
#pragma unroll 4
  for (int t = 0; t < L; ++t) acc = fmaf(lg[t], base[(size_t)t * D + tid], acc);
  utt[(size_t)b * D + tid] = acc;
}

// ---------------------------------------------------------------------------
// Kernel E: sentence GRU (T=1, h0=0) -> dialog_vec = (1-z)*n
// ---------------------------------------------------------------------------
__global__ __launch_bounds__(256) void sent_kernel(
    const float* __restrict__ utt, const float* __restrict__ Wih,
    const float* __restrict__ bih, const float* __restrict__ bhh,
    float* __restrict__ out) {
  __shared__ float u[D];
  const int d = threadIdx.x, b = blockIdx.x;
  u[d] = utt[(size_t)b * D + d];
  __syncthreads();

  const float* wr = Wih + (size_t)d * D;
  const float* wz = Wih + (size_t)(D + d) * D;
  const float* wn = Wih + (size_t)(2 * D + d) * D;
  float ar = 0.0f, az = 0.0f, an = 0.0f;
  for (int k = 0; k < D; k += 4) {
    float4 vr = *(const float4*)(wr + k);
    float4 vz = *(const float4*)(wz + k);
    float4 vn = *(const float4*)(wn + k);
    float u0 = u[k], u1 = u[k + 1], u2 = u[k + 2], u3 = u[k + 3];
    ar += vr.x * u0 + vr.y * u1 + vr.z * u2 + vr.w * u3;
    az += vz.x * u0 + vz.y * u1 + vz.z * u2 + vz.w * u3;
    an += vn.x * u0 + vn.y * u1 + vn.z * u2 + vn.w * u3;
  }
  float xr = ar + bih[d];
  float xz = az + bih[D + d];
  float xn = an + bih[2 * D + d];
  float r = sigm(xr + bhh[d]);
  float z = sigm(xz + bhh[D + d]);
  float n = tanh_f(xn + r * bhh[2 * D + d]);
  out[(size_t)b * D + d] = (1.0f - z) * n;
}

// ---------------------------------------------------------------------------
extern "C" void kernel_launch(void* const* d_in, const int* in_sizes, int n_in,
                              void* d_out, int out_size, void* d_ws, size_t ws_size,
                              hipStream_t stream) {
  const int* tokens    = (const int*)d_in[0];
  const float* embed   = (const float*)d_in[1];
  const float* wg_Wih  = (const float*)d_in[2];
  const float* wg_Whh  = (const float*)d_in[3];
  const float* wg_bih  = (const float*)d_in[4];
  const float* wg_bhh  = (const float*)d_in[5];
  const float* ua_w    = (const float*)d_in[6];
  // d_in[7] ua_b: softmax shift-invariant -> unused
  const float* sg_Wih  = (const float*)d_in[8];
  // d_in[9] sg_Whh: h0 == 0 -> unused
  const float* sg_bih  = (const float*)d_in[10];
  const float* sg_bhh  = (const float*)d_in[11];
  // d_in[12..13] da_w/da_b: softmax over T=1 -> unused
  float* out = (float*)d_out;

  char* ws = (char*)d_ws;
  float* gx  = (float*)ws;                                     // 96 MB
  char* wo_region = ws + (size_t)NUTT * L * G * 4;
  float* wo  = (float*)wo_region;                              // 32 MB
  float* utt = (float*)(wo_region + (size_t)NUTT * L * D * 4); // 64 KB

  // Wih f16 hi/lo split lives at the head of the wo region: it is consumed
  // by gx_gemm_mfma BEFORE gru_scan_word overwrites wo (same stream, ordered).
  _Float16* whi = (_Float16*)wo_region;
  _Float16* wlo = whi + (size_t)G * D;                         // 2 x 384 KB

  split_wih<<<G, 256, 0, stream>>>(wg_Wih, whi, wlo);
  dim3 gB(512, 6);
  gx_gemm_mfma<<<gB, 256, 0, stream>>>(tokens, embed, whi, wlo, wg_bih, gx);
  gru_scan_word<<<NUTT, 512, 0, stream>>>(gx, wg_Whh, wg_bhh, wo);
  attn_pool_word<<<NUTT, 256, 0, stream>>>(wo, ua_w, utt);
  sent_kernel<<<NUTT, 256, 0, stream>>>(utt, sg_Wih, sg_bih, sg_bhh, out);
}